// Round 7
// baseline (1850.190 us; speedup 1.0000x reference)
//
#include <hip/hip_runtime.h>
#include <hip/hip_bf16.h>

#define D 128
#define BK 64   // dst nodes per bucket

__device__ __forceinline__ float bf2f(unsigned short u) {
    union { unsigned int i; float f; } c;
    c.i = ((unsigned int)u) << 16;
    return c.f;
}
__device__ __forceinline__ float bits2f(unsigned int i) {
    union { unsigned int i; float f; } c;
    c.i = i;
    return c.f;
}
__device__ __forceinline__ unsigned short f2bf(float f) {
    __hip_bfloat16 h = __float2bfloat16(f);
    return *(unsigned short*)&h;
}

// Probe dtypes at runtime (one wave). flags[0]=1 if x is fp32; flags[1]=1 if ei is int64.
__global__ __launch_bounds__(64) void probe_kernel(
    const unsigned short* __restrict__ x,
    const long long* __restrict__ ei64,
    int nNodes, int* __restrict__ flags)
{
    const int lane = threadIdx.x;
    int cnt = 0;
    for (int i = lane; i < 512; i += 64) {
        float v = bf2f(x[i]);
        if (!(fabsf(v) < 1e4f)) cnt++;   // NaN counts
    }
    unsigned long long m1 = __ballot(cnt > 0);
    long long v = ei64[lane];
    int bad = (v < 0 || v >= (long long)nNodes) ? 1 : 0;
    unsigned long long m2 = __ballot(bad);
    if (lane == 0) {
        flags[0] = (__popcll(m1) > 2) ? 1 : 0;
        flags[1] = (m2 == 0) ? 1 : 0;
    }
}

// ---------- GEMM: out = in @ W (+ b). Register-blocked 64-row tiles. ----------
// in_f32 / out_f32: 1 = fp32, 0 = bf16, -1 = follow flags[0].
__global__ __launch_bounds__(256) void gemm_kernel(
    const void* __restrict__ inv, const void* __restrict__ Wv,
    const void* __restrict__ bv, void* __restrict__ outv,
    int nNodes, const int* __restrict__ flags,
    int in_f32p, int out_f32p, int add_bias)
{
    __shared__ float Ws[D * D];   // 64 KB
    __shared__ float bs[D];

    const int xf32 = flags[0];
    const int in_f32  = (in_f32p  < 0) ? xf32 : in_f32p;
    const int out_f32 = (out_f32p < 0) ? xf32 : out_f32p;

    if (xf32) {   // W/b dtype follows x dtype
        const float* W = (const float*)Wv;
        for (int i = threadIdx.x; i < D * D; i += 256) Ws[i] = W[i];
        if (threadIdx.x < D)
            bs[threadIdx.x] = add_bias ? ((const float*)bv)[threadIdx.x] : 0.f;
    } else {
        const unsigned short* W = (const unsigned short*)Wv;
        for (int i = threadIdx.x; i < D * D; i += 256) Ws[i] = bf2f(W[i]);
        if (threadIdx.x < D)
            bs[threadIdx.x] = add_bias ? bf2f(((const unsigned short*)bv)[threadIdx.x]) : 0.f;
    }
    __syncthreads();

    const int cg = threadIdx.x & 31;
    const int rg = threadIdx.x >> 5;
    const int c = cg * 4;
    const int row0 = blockIdx.x * 64 + rg * 8;

    size_t rIdx[8];
    #pragma unroll
    for (int r = 0; r < 8; ++r) {
        int row = row0 + r;
        rIdx[r] = (size_t)(row < nNodes ? row : nNodes - 1);
    }

    float4 acc[8];
    #pragma unroll
    for (int r = 0; r < 8; ++r)
        acc[r] = make_float4(bs[c], bs[c + 1], bs[c + 2], bs[c + 3]);

    if (in_f32) {
        const float* in = (const float*)inv;
        for (int k = 0; k < D; k += 4) {
            float4 w0 = *(const float4*)&Ws[(k + 0) * D + c];
            float4 w1 = *(const float4*)&Ws[(k + 1) * D + c];
            float4 w2 = *(const float4*)&Ws[(k + 2) * D + c];
            float4 w3 = *(const float4*)&Ws[(k + 3) * D + c];
            #pragma unroll
            for (int r = 0; r < 8; ++r) {
                float4 a = *(const float4*)(in + rIdx[r] * D + k);
                acc[r].x += a.x * w0.x + a.y * w1.x + a.z * w2.x + a.w * w3.x;
                acc[r].y += a.x * w0.y + a.y * w1.y + a.z * w2.y + a.w * w3.y;
                acc[r].z += a.x * w0.z + a.y * w1.z + a.z * w2.z + a.w * w3.z;
                acc[r].w += a.x * w0.w + a.y * w1.w + a.z * w2.w + a.w * w3.w;
            }
        }
    } else {
        const unsigned short* in = (const unsigned short*)inv;
        for (int k = 0; k < D; k += 4) {
            float4 w0 = *(const float4*)&Ws[(k + 0) * D + c];
            float4 w1 = *(const float4*)&Ws[(k + 1) * D + c];
            float4 w2 = *(const float4*)&Ws[(k + 2) * D + c];
            float4 w3 = *(const float4*)&Ws[(k + 3) * D + c];
            #pragma unroll
            for (int r = 0; r < 8; ++r) {
                ushort4 u = *(const ushort4*)(in + rIdx[r] * D + k);
                float ax = bf2f(u.x), ay = bf2f(u.y), az = bf2f(u.z), aw = bf2f(u.w);
                acc[r].x += ax * w0.x + ay * w1.x + az * w2.x + aw * w3.x;
                acc[r].y += ax * w0.y + ay * w1.y + az * w2.y + aw * w3.y;
                acc[r].z += ax * w0.z + ay * w1.z + az * w2.z + aw * w3.z;
                acc[r].w += ax * w0.w + ay * w1.w + az * w2.w + aw * w3.w;
            }
        }
    }

    #pragma unroll
    for (int r = 0; r < 8; ++r) {
        int row = row0 + r;
        if (row >= nNodes) break;
        if (out_f32) {
            ((float4*)outv)[(size_t)row * 32 + cg] = acc[r];
        } else {
            ushort4 o;
            o.x = f2bf(acc[r].x); o.y = f2bf(acc[r].y);
            o.z = f2bf(acc[r].z); o.w = f2bf(acc[r].w);
            ((ushort4*)outv)[(size_t)row * 32 + cg] = o;
        }
    }
}

// ---------- bucket CSR: count / scan / fill ----------
__global__ __launch_bounds__(256) void count_kernel(
    const void* __restrict__ eiv, int* __restrict__ bins, int nEdges,
    const int* __restrict__ flags)
{
    int e = blockIdx.x * 256 + threadIdx.x;
    if (e >= nEdges) return;
    int d;
    if (flags[1]) d = (int)((const long long*)eiv)[(size_t)nEdges + e];
    else          d = ((const int*)eiv)[(size_t)nEdges + e];
    atomicAdd(&bins[d >> 6], 1);
}

// One block; nb up to ~16K. bins -> cursors (=starts); starts[nb] = nEdges.
__global__ __launch_bounds__(1024) void scan_bins(
    int* __restrict__ bins, int* __restrict__ starts, int nb)
{
    __shared__ int bufA[1024];
    __shared__ int bufB[1024];
    const int t = threadIdx.x;
    const int chunk = (nb + 1023) / 1024;
    const int lo = t * chunk;
    const int hi = min(lo + chunk, nb);

    int s = 0;
    for (int i = lo; i < hi; ++i) s += bins[i];
    bufA[t] = s;
    __syncthreads();
    int* in = bufA;
    int* out = bufB;
    for (int step = 1; step < 1024; step <<= 1) {
        int v = in[t];
        if (t >= step) v += in[t - step];
        out[t] = v;
        __syncthreads();
        int* tmp = in; in = out; out = tmp;
    }
    int off = in[t] - s;   // exclusive
    for (int i = lo; i < hi; ++i) {
        int c = bins[i];
        starts[i] = off;
        bins[i] = off;     // becomes cursor
        off += c;
    }
    if (t == 1023) starts[nb] = off;
}

__global__ __launch_bounds__(256) void fill_kernel(
    const void* __restrict__ eiv, int* __restrict__ cursors,
    unsigned int* __restrict__ ebuf, int nEdges, const int* __restrict__ flags)
{
    int e = blockIdx.x * 256 + threadIdx.x;
    if (e >= nEdges) return;
    int s, d;
    if (flags[1]) {
        const long long* ei = (const long long*)eiv;
        s = (int)ei[e];
        d = (int)ei[(size_t)nEdges + e];
    } else {
        const int* ei = (const int*)eiv;
        s = ei[e];
        d = ei[(size_t)nEdges + e];
    }
    int pos = atomicAdd(&cursors[d >> 6], 1);
    ebuf[pos] = ((unsigned int)(d & 63) << 24) | (unsigned int)s;   // needs N < 2^24
}

// ---------- aggregate: one block per bucket; LDS fp32 accumulators ----------
// accE holds even cols (2l), accO odd cols (2l+1): bank-conflict-free LDS atomics.
__global__ __launch_bounds__(256) void agg_kernel(
    const unsigned int* __restrict__ yu,      // y bf16 pairs: N x 64 uints
    const int* __restrict__ starts, const unsigned int* __restrict__ ebuf,
    const void* __restrict__ bv, void* __restrict__ outv,
    int nNodes, const int* __restrict__ flags)
{
    __shared__ float accE[BK * 64];   // 16 KB
    __shared__ float accO[BK * 64];   // 16 KB

    for (int i = threadIdx.x; i < BK * 64; i += 256) {
        accE[i] = 0.f;
        accO[i] = 0.f;
    }
    __syncthreads();

    const int wave = threadIdx.x >> 6;
    const int lane = threadIdx.x & 63;
    const int beg = starts[blockIdx.x];
    const int end = starts[blockIdx.x + 1];
    const int cnt = end - beg;
    const int chunk = (cnt + 3) >> 2;
    const int wbeg = beg + wave * chunk;
    const int wend = min(wbeg + chunk, end);

    for (int base = wbeg; base < wend; base += 64) {
        const int m = min(64, wend - base);
        unsigned int pe = (base + lane < wend) ? ebuf[base + lane] : 0u;

        for (int t = 0; t < m; t += 4) {
            const int n4 = min(4, m - t);
            unsigned int pk[4], u[4];
            #pragma unroll
            for (int j = 0; j < 4; ++j) pk[j] = __shfl(pe, t + j);
            #pragma unroll
            for (int j = 0; j < 4; ++j) {
                if (j < n4) u[j] = yu[(size_t)(pk[j] & 0xFFFFFFu) * 64 + lane];
            }
            #pragma unroll
            for (int j = 0; j < 4; ++j) {
                if (j < n4) {
                    const int dl = (int)(pk[j] >> 24);
                    atomicAdd(&accE[dl * 64 + lane], bits2f(u[j] << 16));
                    atomicAdd(&accO[dl * 64 + lane], bits2f(u[j] & 0xFFFF0000u));
                }
            }
        }
    }
    __syncthreads();

    // writeback: bias + cast; coalesced (uint or float2 per thread)
    const int xf32 = flags[0];
    const int node0 = blockIdx.x * BK;
    for (int i = threadIdx.x; i < BK * 64; i += 256) {
        const int dl = i >> 6;
        const int l  = i & 63;
        const int node = node0 + dl;
        if (node >= nNodes) break;
        float ox = accE[dl * 64 + l];
        float oy = accO[dl * 64 + l];
        if (xf32) {
            float2 bb = ((const float2*)bv)[l];
            float2 o; o.x = ox + bb.x; o.y = oy + bb.y;
            ((float2*)outv)[(size_t)node * 64 + l] = o;
        } else {
            unsigned int ub = ((const unsigned int*)bv)[l];
            ox += bits2f(ub << 16);
            oy += bits2f(ub & 0xFFFF0000u);
            unsigned int o = ((unsigned int)f2bf(ox)) | (((unsigned int)f2bf(oy)) << 16);
            ((unsigned int*)outv)[(size_t)node * 64 + l] = o;
        }
    }
}

// ---------- fallback scatter (atomics) ----------
__global__ __launch_bounds__(256) void scatter_kernel(
    const void* __restrict__ xv, const void* __restrict__ eiv,
    float* __restrict__ agg, int nEdges, const int* __restrict__ flags)
{
    long long tid = (long long)blockIdx.x * 256 + threadIdx.x;
    int e = (int)(tid >> 5);
    if (e >= nEdges) return;
    int q = (int)tid & 31;

    const int xf32 = flags[0];
    int s, d;
    if (flags[1]) {
        const long long* ei = (const long long*)eiv;
        s = (int)ei[e]; d = (int)ei[(size_t)nEdges + e];
    } else {
        const int* ei = (const int*)eiv;
        s = ei[e]; d = ei[(size_t)nEdges + e];
    }
    float4 v;
    if (xf32) {
        v = ((const float4*)xv)[(size_t)s * 32 + q];
    } else {
        ushort4 u = ((const ushort4*)xv)[(size_t)s * 32 + q];
        v.x = bf2f(u.x); v.y = bf2f(u.y); v.z = bf2f(u.z); v.w = bf2f(u.w);
    }
    float* ap = agg + (size_t)d * D + q * 4;
    atomicAdd(ap + 0, v.x);
    atomicAdd(ap + 1, v.y);
    atomicAdd(ap + 2, v.z);
    atomicAdd(ap + 3, v.w);
}

static inline size_t alignup(size_t v, size_t a) { return (v + a - 1) & ~(a - 1); }

extern "C" void kernel_launch(void* const* d_in, const int* in_sizes, int n_in,
                              void* d_out, int out_size, void* d_ws, size_t ws_size,
                              hipStream_t stream) {
    const void* x  = d_in[0];
    const void* ei = d_in[1];
    const void* W  = d_in[2];
    const void* b  = d_in[3];

    const int nNodes = in_sizes[0] / D;
    const int nEdges = in_sizes[1] / 2;
    const int nb = (nNodes + BK - 1) / BK;

    int* flags = (int*)d_ws;
    probe_kernel<<<1, 64, 0, stream>>>((const unsigned short*)x, (const long long*)ei,
                                       nNodes, flags);

    // fast path ws: flags(512) | bins[nb] | starts[nb+1] | ebuf[E] | y[N*D] bf16
    size_t off_bins   = 512;
    size_t off_starts = alignup(off_bins + 4ull * nb, 256);
    size_t off_ebuf   = alignup(off_starts + 4ull * (nb + 1), 256);
    size_t off_y      = alignup(off_ebuf + 4ull * nEdges, 512);
    size_t need_fast  = off_y + (size_t)nNodes * D * 2;

    const int eblocks = (nEdges + 255) / 256;
    const int mblocks = (nNodes + 63) / 64;

    if (ws_size >= need_fast && nNodes < (1 << 24)) {
        int*          bins   = (int*)((char*)d_ws + off_bins);
        int*          starts = (int*)((char*)d_ws + off_starts);
        unsigned int* ebuf   = (unsigned int*)((char*)d_ws + off_ebuf);
        void*         y      = (void*)((char*)d_ws + off_y);

        // y = x @ W (no bias), stored bf16
        gemm_kernel<<<mblocks, 256, 0, stream>>>(x, W, b, y, nNodes, flags,
                                                 /*in_f32*/-1, /*out_f32*/0, /*bias*/0);

        hipMemsetAsync(bins, 0, 4ull * nb, stream);
        count_kernel<<<eblocks, 256, 0, stream>>>(ei, bins, nEdges, flags);
        scan_bins<<<1, 1024, 0, stream>>>(bins, starts, nb);
        fill_kernel<<<eblocks, 256, 0, stream>>>(ei, bins, ebuf, nEdges, flags);

        agg_kernel<<<nb, 256, 0, stream>>>((const unsigned int*)y, starts, ebuf,
                                           b, d_out, nNodes, flags);
    } else {
        // fallback: atomic scatter into fp32 agg, then out = agg @ W + b
        float* agg = (float*)((char*)d_ws + 512);
        hipMemsetAsync(agg, 0, (size_t)nNodes * D * sizeof(float), stream);
        long long total = (long long)nEdges * 32;
        int sblocks = (int)((total + 255) / 256);
        scatter_kernel<<<sblocks, 256, 0, stream>>>(x, ei, agg, nEdges, flags);
        gemm_kernel<<<mblocks, 256, 0, stream>>>(agg, W, b, d_out, nNodes, flags,
                                                 /*in_f32*/1, /*out_f32*/-1, /*bias*/1);
    }
}